// Round 6
// baseline (90.289 us; speedup 1.0000x reference)
//
#include <hip/hip_runtime.h>

typedef __attribute__((ext_vector_type(8))) short          bf16x8;   // MFMA A/B frag
typedef __attribute__((ext_vector_type(8))) unsigned short u16x8;
typedef __attribute__((ext_vector_type(4))) float          f32x4;    // MFMA C/D frag

#define Bn 16
#define IC 32
#define OC 64
#define Hh 128
#define Ww 128
#define ROWS 4            // output rows per block
#define INROWS (ROWS + 2) // staged rows incl. halo
#define CP 132            // padded col count; LDS col = gx+1, cols 0..129 used

__device__ inline unsigned short f2b(float f) {
    unsigned u = __builtin_bit_cast(unsigned, f);
    return (unsigned short)((u + 0x7FFFu + ((u >> 16) & 1u)) >> 16);
}

__device__ inline unsigned cvtpk(float a, float b) {
    unsigned r;
    asm("v_cvt_pk_bf16_f32 %0, %1, %2" : "=v"(r) : "v"(a), "v"(b));
    return r;
}

// ---- prep: w OIHW fp32 -> bf16 [dydx][oc][ic] frag table (36 KB, L2) ----
__global__ void prep_w(const float* __restrict__ w, unsigned short* __restrict__ wf)
{
    int idx = blockIdx.x * 256 + threadIdx.x;        // 0 .. 18431
    int dydx = idx / (OC * IC);
    int rem  = idx - dydx * (OC * IC);               // oc*32 + ic
    wf[idx] = f2b(w[(size_t)rem * 9 + dydx]);
}

// ---- fused conv: hoisted staging loads, XCD-chunked block map ----------
// LDS layout [row][icg][col][ic8]: staging writes 16B/lane contiguous,
// A-frag reads 256B-contiguous per 16-lane group (balanced banks).
__global__ __launch_bounds__(256, 2)
void conv_fused(const float* __restrict__ x,
                const unsigned short* __restrict__ wf,
                const float* __restrict__ bias,
                float* __restrict__ out)
{
    __shared__ __align__(16) unsigned short xs[INROWS * 4 * CP * 8]; // 50688 B

    const int tid  = threadIdx.x;
    const int lane = tid & 63;
    const int wid  = tid >> 6;
    const int llo  = lane & 15;
    const int lhi  = lane >> 4;

    // XCD-chunked remap: hw round-robins bid%8 across XCDs; give each XCD
    // 64 consecutive logical blocks (= 2 whole images) so halo rows and the
    // weight table stay L2-resident per XCD.
    const int hw      = blockIdx.x + blockIdx.y * gridDim.x;   // 0..511
    const int logical = (hw & 7) * 64 + (hw >> 3);
    const int b  = logical >> 5;
    const int y0 = (logical & 31) * ROWS;

    // zero halo columns (gx = -1 -> col 0, gx = 128 -> col 129)
    if (tid < 48) {
        int r = tid >> 3, rest = tid & 7;
        int icg = rest & 3;
        int col = (rest >> 2) ? 129 : 0;
        *(u16x8*)&xs[((r * 4 + icg) * CP + col) * 8] = (u16x8){0,0,0,0,0,0,0,0};
    }

    // ---- issue ALL 24 staging loads first (no waits between issues) ----
    // task = (row, icg, 4-col group); wave-uniform row -> uniform branch.
    const float* xb0 = x + (size_t)b * IC * Hh * Ww;
    f32x4 v[3][8];
    int   dbase[3];
    #pragma unroll
    for (int i = 0; i < 3; ++i) {                     // 6*4*32 / 256 = 3
        int task = tid + i * 256;
        int cg   = task & 31;
        int icg  = (task >> 5) & 3;
        int row  = task >> 7;
        int gy   = y0 - 1 + row;
        int col0 = cg * 4;
        dbase[i] = ((row * 4 + icg) * CP + col0 + 1) * 8;
        if ((unsigned)gy < 128u) {
            const float* sp = xb0 + ((size_t)(icg * 8) * Hh + gy) * Ww + col0;
            #pragma unroll
            for (int j = 0; j < 8; ++j)
                v[i][j] = *(const f32x4*)(sp + (size_t)j * Hh * Ww);
        } else {
            #pragma unroll
            for (int j = 0; j < 8; ++j) v[i][j] = (f32x4){0.f, 0.f, 0.f, 0.f};
        }
    }

    // ---- convert + write (vmcnt waits overlap across the 3 groups) ----
    #pragma unroll
    for (int i = 0; i < 3; ++i) {
        unsigned short* base = &xs[dbase[i]];
        #pragma unroll
        for (int c = 0; c < 4; ++c) {
            unsigned pk[4];
            #pragma unroll
            for (int jp = 0; jp < 4; ++jp)
                pk[jp] = cvtpk(v[i][2 * jp][c], v[i][2 * jp + 1][c]);
            *(u16x8*)(base + c * 8) = *(const u16x8*)&pk[0];
        }
    }

    // ---- B-fragments from pre-transposed table (L2-resident) ----
    bf16x8 bw[9][4];
    #pragma unroll
    for (int dydx = 0; dydx < 9; ++dydx)
        #pragma unroll
        for (int nf = 0; nf < 4; ++nf)
            bw[dydx][nf] = *(const bf16x8*)&wf[((dydx * 4 + nf) * 16 + llo) * IC + lhi * 8];

    float bias_s[4];
    #pragma unroll
    for (int nf = 0; nf < 4; ++nf) bias_s[nf] = bias[nf * 16 + llo];

    __syncthreads();

    const int px0 = wid * 32;
    for (int r = 0; r < ROWS; ++r) {
        f32x4 acc[2][4];
        #pragma unroll
        for (int m = 0; m < 2; ++m)
            #pragma unroll
            for (int nf = 0; nf < 4; ++nf)
                acc[m][nf] = (f32x4){0.f, 0.f, 0.f, 0.f};

        #pragma unroll
        for (int dy = 0; dy < 3; ++dy) {
            #pragma unroll
            for (int dx = 0; dx < 3; ++dx) {
                const int dydx = dy * 3 + dx;
                bf16x8 a0 = *(const bf16x8*)&xs[(((r + dy) * 4 + lhi) * CP + px0 + llo + dx) * 8];
                bf16x8 a1 = *(const bf16x8*)&xs[(((r + dy) * 4 + lhi) * CP + px0 + 16 + llo + dx) * 8];
                #pragma unroll
                for (int nf = 0; nf < 4; ++nf) {
                    acc[0][nf] = __builtin_amdgcn_mfma_f32_16x16x32_bf16(a0, bw[dydx][nf], acc[0][nf], 0, 0, 0);
                    acc[1][nf] = __builtin_amdgcn_mfma_f32_16x16x32_bf16(a1, bw[dydx][nf], acc[1][nf], 0, 0, 0);
                }
            }
        }

        // epilogue: bias, min over 64 oc (4 frags in-reg + 4 shfl), x2, store
        #pragma unroll
        for (int m = 0; m < 2; ++m) {
            f32x4 vout;
            #pragma unroll
            for (int j = 0; j < 4; ++j) {
                float vmin = fminf(fminf(acc[m][0][j] + bias_s[0], acc[m][1][j] + bias_s[1]),
                                   fminf(acc[m][2][j] + bias_s[2], acc[m][3][j] + bias_s[3]));
                vmin = fminf(vmin, __shfl_xor(vmin, 1, 64));
                vmin = fminf(vmin, __shfl_xor(vmin, 2, 64));
                vmin = fminf(vmin, __shfl_xor(vmin, 4, 64));
                vmin = fminf(vmin, __shfl_xor(vmin, 8, 64));
                vout[j] = vmin * 2.0f;
            }
            if (llo == 0) {
                float* op = out + ((size_t)b * Hh + (y0 + r)) * Ww + px0 + m * 16 + lhi * 4;
                *(f32x4*)op = vout;
            }
        }
    }
}

extern "C" void kernel_launch(void* const* d_in, const int* in_sizes, int n_in,
                              void* d_out, int out_size, void* d_ws, size_t ws_size,
                              hipStream_t stream)
{
    const float* x    = (const float*)d_in[0];
    const float* w    = (const float*)d_in[1];
    const float* bias = (const float*)d_in[2];
    float* out        = (float*)d_out;

    unsigned short* wfr = (unsigned short*)d_ws;      // 36 KB frag table

    prep_w<<<dim3(9 * OC * IC / 256), 256, 0, stream>>>(w, wfr);
    conv_fused<<<dim3(Hh / ROWS, Bn), 256, 0, stream>>>(x, wfr, bias, out);
}

// Round 7
// 88.518 us; speedup vs baseline: 1.0200x; 1.0200x over previous
//
#include <hip/hip_runtime.h>

typedef __attribute__((ext_vector_type(8))) short          bf16x8;   // MFMA A/B frag
typedef __attribute__((ext_vector_type(8))) unsigned short u16x8;
typedef __attribute__((ext_vector_type(4))) float          f32x4;    // MFMA C/D frag

#define Bn 16
#define IC 32
#define OC 64
#define Hh 128
#define Ww 128
#define ROWS 4            // output rows per block
#define INROWS (ROWS + 2) // staged rows incl. halo
#define CP 132            // padded col count; LDS col = gx+1, cols 0..129 used

__device__ inline unsigned short f2b(float f) {
    unsigned u = __builtin_bit_cast(unsigned, f);
    return (unsigned short)((u + 0x7FFFu + ((u >> 16) & 1u)) >> 16);
}

__device__ inline unsigned cvtpk(float a, float b) {
    unsigned r;
    asm("v_cvt_pk_bf16_f32 %0, %1, %2" : "=v"(r) : "v"(a), "v"(b));
    return r;
}

// ---- prep: w OIHW fp32 -> bf16 [dydx][oc][ic] frag table (36 KB, L2) ----
__global__ void prep_w(const float* __restrict__ w, unsigned short* __restrict__ wf)
{
    int idx = blockIdx.x * 256 + threadIdx.x;        // 0 .. 18431
    int dydx = idx / (OC * IC);
    int rem  = idx - dydx * (OC * IC);               // oc*32 + ic
    wf[idx] = f2b(w[(size_t)rem * 9 + dydx]);
}

// ---- fused: NCHW fp32 -> LDS bf16 (vectorized), 9 shifted MFMAs, min ----
// LDS layout [row][icg][col][ic8]: staging ds_write_b128 16B/lane contiguous,
// A-frag ds_read_b128 256B-contiguous per 16-lane group (balanced banks).
__global__ __launch_bounds__(256, 2)
void conv_fused(const float* __restrict__ x,
                const unsigned short* __restrict__ wf,
                const float* __restrict__ bias,
                float* __restrict__ out)
{
    __shared__ __align__(16) unsigned short xs[INROWS * 4 * CP * 8]; // 50688 B

    const int tid  = threadIdx.x;
    const int lane = tid & 63;
    const int wid  = tid >> 6;
    const int llo  = lane & 15;
    const int lhi  = lane >> 4;
    const int b    = blockIdx.y;
    const int y0   = blockIdx.x * ROWS;

    // ---- B-fragments + bias issued FIRST: L2 latency hides under staging ----
    bf16x8 bw[9][4];
    #pragma unroll
    for (int dydx = 0; dydx < 9; ++dydx)
        #pragma unroll
        for (int nf = 0; nf < 4; ++nf)
            bw[dydx][nf] = *(const bf16x8*)&wf[((dydx * 4 + nf) * 16 + llo) * IC + lhi * 8];

    float bias_s[4];
    #pragma unroll
    for (int nf = 0; nf < 4; ++nf) bias_s[nf] = bias[nf * 16 + llo];

    // zero halo columns (gx = -1 -> col 0, gx = 128 -> col 129)
    if (tid < 48) {
        int r = tid >> 3, rest = tid & 7;
        int icg = rest & 3;
        int col = (rest >> 2) ? 129 : 0;
        *(u16x8*)&xs[((r * 4 + icg) * CP + col) * 8] = (u16x8){0,0,0,0,0,0,0,0};
    }

    // ---- stage: task = (row, icg, 4-col group); 8x dwordx4 loads,
    //      16x cvt_pk, 4x ds_write_b128 per task; 3 tasks/thread ----
    const float* xb0 = x + (size_t)b * IC * Hh * Ww;
    #pragma unroll
    for (int i = 0; i < 3; ++i) {                     // 6*4*32 / 256 = 3
        int task = tid + i * 256;
        int cg   = task & 31;                         // 4-col group
        int icg  = (task >> 5) & 3;
        int row  = task >> 7;
        int gy   = y0 - 1 + row;
        int col0 = cg * 4;

        f32x4 v[8];
        if ((unsigned)gy < 128u) {
            const float* sp = xb0 + ((size_t)(icg * 8) * Hh + gy) * Ww + col0;
            #pragma unroll
            for (int j = 0; j < 8; ++j)
                v[j] = *(const f32x4*)(sp + (size_t)j * Hh * Ww);
        } else {
            #pragma unroll
            for (int j = 0; j < 8; ++j) v[j] = (f32x4){0.f, 0.f, 0.f, 0.f};
        }

        unsigned short* base = &xs[((row * 4 + icg) * CP + col0 + 1) * 8];
        #pragma unroll
        for (int c = 0; c < 4; ++c) {
            unsigned pk[4];
            #pragma unroll
            for (int jp = 0; jp < 4; ++jp)
                pk[jp] = cvtpk(v[2 * jp][c], v[2 * jp + 1][c]);
            *(u16x8*)(base + c * 8) = *(const u16x8*)&pk[0];
        }
    }

    __syncthreads();

    const int px0 = wid * 32;
    for (int r = 0; r < ROWS; ++r) {
        f32x4 acc[2][4];
        #pragma unroll
        for (int m = 0; m < 2; ++m)
            #pragma unroll
            for (int nf = 0; nf < 4; ++nf)
                acc[m][nf] = (f32x4){0.f, 0.f, 0.f, 0.f};

        #pragma unroll
        for (int dy = 0; dy < 3; ++dy) {
            #pragma unroll
            for (int dx = 0; dx < 3; ++dx) {
                const int dydx = dy * 3 + dx;
                bf16x8 a0 = *(const bf16x8*)&xs[(((r + dy) * 4 + lhi) * CP + px0 + llo + dx) * 8];
                bf16x8 a1 = *(const bf16x8*)&xs[(((r + dy) * 4 + lhi) * CP + px0 + 16 + llo + dx) * 8];
                #pragma unroll
                for (int nf = 0; nf < 4; ++nf) {
                    acc[0][nf] = __builtin_amdgcn_mfma_f32_16x16x32_bf16(a0, bw[dydx][nf], acc[0][nf], 0, 0, 0);
                    acc[1][nf] = __builtin_amdgcn_mfma_f32_16x16x32_bf16(a1, bw[dydx][nf], acc[1][nf], 0, 0, 0);
                }
            }
        }

        // epilogue: bias, min over 64 oc (4 frags in-reg + 4 shfl), x2, store
        #pragma unroll
        for (int m = 0; m < 2; ++m) {
            f32x4 vout;
            #pragma unroll
            for (int j = 0; j < 4; ++j) {
                float v = fminf(fminf(acc[m][0][j] + bias_s[0], acc[m][1][j] + bias_s[1]),
                                fminf(acc[m][2][j] + bias_s[2], acc[m][3][j] + bias_s[3]));
                v = fminf(v, __shfl_xor(v, 1, 64));
                v = fminf(v, __shfl_xor(v, 2, 64));
                v = fminf(v, __shfl_xor(v, 4, 64));
                v = fminf(v, __shfl_xor(v, 8, 64));
                vout[j] = v * 2.0f;
            }
            if (llo == 0) {
                float* op = out + ((size_t)b * Hh + (y0 + r)) * Ww + px0 + m * 16 + lhi * 4;
                *(f32x4*)op = vout;
            }
        }
    }
}

extern "C" void kernel_launch(void* const* d_in, const int* in_sizes, int n_in,
                              void* d_out, int out_size, void* d_ws, size_t ws_size,
                              hipStream_t stream)
{
    const float* x    = (const float*)d_in[0];
    const float* w    = (const float*)d_in[1];
    const float* bias = (const float*)d_in[2];
    float* out        = (float*)d_out;

    unsigned short* wfr = (unsigned short*)d_ws;      // 36 KB frag table

    prep_w<<<dim3(9 * OC * IC / 256), 256, 0, stream>>>(w, wfr);
    conv_fused<<<dim3(Hh / ROWS, Bn), 256, 0, stream>>>(x, wfr, bias, out);
}